// Round 3
// baseline (463.397 us; speedup 1.0000x reference)
//
#include <hip/hip_runtime.h>

#define LOG2E 1.4426950408889634f
#define LN2   0.6931471805599453f

typedef __attribute__((ext_vector_type(2))) float f32x2;

// One wave (64 lanes) per batch element. Lane i owns state i.
// Log2-domain recurrence:
//   score2'[i] = emit2[i] + a2 + log2( sum_j M[i,j] * 2^(score2[j]-a2) )
// M rows live in 32 f32x2 VGPR pairs per lane. The matvec inner loop uses
// v_pk_fma_f32 (double-pumped FP32: 2 FMAs/lane/instr) with the broadcast
// w-pair in an SGPR pair filled by two v_readlane_b32. Two SGPR pairs
// (s[80:81], s[84:85]) alternate so each readlane has >=3 instructions of
// distance before its consuming pk_fma (explicit software pipeline).
//
// Round-2 post-mortem: VGPR fix confirmed (48->132) but only -5% time:
// step = 583 cyc vs ~290 issue -> issue count + RL->FMA scheduling is the
// bottleneck, not residency. pk_fma cuts issue 128->96 instrs and the asm
// pipeline pins the hazard distance.
__device__ __forceinline__ float bcast_first(float v) {
  return __uint_as_float(__builtin_amdgcn_readfirstlane(__float_as_uint(v)));
}

// fma current pair from SPAIR, then refill SPAIR's registers for pair p+2.
#define PKFMA_RL(ACC, MPAIR, SPAIR, S0, S1, W, J0, J1)              \
  asm volatile("v_pk_fma_f32 %0, %1, " SPAIR ", %0\n\t"             \
               "v_readlane_b32 " S0 ", %2, %3\n\t"                  \
               "v_readlane_b32 " S1 ", %2, %4"                      \
               : "+v"(ACC)                                          \
               : "v"(MPAIR), "v"(W), "n"(J0), "n"(J1)               \
               : S0, S1)

#define PKFMA_ONLY(ACC, MPAIR, SPAIR)                               \
  asm volatile("v_pk_fma_f32 %0, %1, " SPAIR ", %0"                 \
               : "+v"(ACC) : "v"(MPAIR))

// pairs p=4g..4g+3: even p consume s[80:81], odd consume s[84:85];
// each refills for p+2 (j = 2p+4, 2p+5).
#define G4(g)                                                              \
  PKFMA_RL(ac0, Mp[4*(g)+0], "s[80:81]", "s80", "s81", w, 8*(g)+4, 8*(g)+5); \
  PKFMA_RL(ac1, Mp[4*(g)+1], "s[84:85]", "s84", "s85", w, 8*(g)+6, 8*(g)+7); \
  PKFMA_RL(ac2, Mp[4*(g)+2], "s[80:81]", "s80", "s81", w, 8*(g)+8, 8*(g)+9); \
  PKFMA_RL(ac3, Mp[4*(g)+3], "s[84:85]", "s84", "s85", w, 8*(g)+10, 8*(g)+11)

__global__ __launch_bounds__(64)
__attribute__((amdgpu_waves_per_eu(1, 1)))
void crf_fwd_33852932227637(
    const float* __restrict__ h,
    const float* __restrict__ trans,
    const int* __restrict__ lengths,
    float* __restrict__ out,
    int T) {
  constexpr int N = 64;
  const int b = blockIdx.x;
  const int lane = threadIdx.x;

  const float* hb = h + (size_t)b * T * N;

  // M row for this lane as 32 f32x2 pairs: Mp[p] = {exp(tr[2p]), exp(tr[2p+1])}
  f32x2 Mp[N / 2];
  const float4* trow = (const float4*)(trans + lane * N);
#pragma unroll
  for (int q = 0; q < 16; ++q) {
    float4 tq = trow[q];
    Mp[2 * q + 0].x = __builtin_amdgcn_exp2f(tq.x * LOG2E);
    Mp[2 * q + 0].y = __builtin_amdgcn_exp2f(tq.y * LOG2E);
    Mp[2 * q + 1].x = __builtin_amdgcn_exp2f(tq.z * LOG2E);
    Mp[2 * q + 1].y = __builtin_amdgcn_exp2f(tq.w * LOG2E);
  }
  // Pin every pair into aligned arch-VGPR pairs before the time loop.
#pragma unroll
  for (int q = 0; q < 8; ++q) {
    asm volatile("" : "+v"(Mp[4 * q + 0]), "+v"(Mp[4 * q + 1]),
                      "+v"(Mp[4 * q + 2]), "+v"(Mp[4 * q + 3]));
  }

  const int len = lengths[b];

  // t=0 closed form (exp(-10000+x)==0 in fp32): score[i]=h[b,0,i]+trans[i,START]
  float score2 = (hb[lane] + trans[lane * N + (N - 2)]) * LOG2E;

  auto step = [&](float emit2) {
    float anch = bcast_first(score2);
    float w = __builtin_amdgcn_exp2f(score2 - anch);
    f32x2 ac0 = {0.f, 0.f}, ac1 = {0.f, 0.f}, ac2 = {0.f, 0.f}, ac3 = {0.f, 0.f};
    // prologue: pairs 0 (w0,w1)->s[80:81], 1 (w2,w3)->s[84:85]
    asm volatile("v_readlane_b32 s80, %0, 0\n\t"
                 "v_readlane_b32 s81, %0, 1\n\t"
                 "v_readlane_b32 s84, %0, 2\n\t"
                 "v_readlane_b32 s85, %0, 3"
                 :: "v"(w) : "s80", "s81", "s84", "s85");
    G4(0); G4(1); G4(2); G4(3); G4(4); G4(5); G4(6);
    // g=7: pairs 28,29 still refill (j=60..63); 30,31 consume only.
    PKFMA_RL(ac0, Mp[28], "s[80:81]", "s80", "s81", w, 60, 61);
    PKFMA_RL(ac1, Mp[29], "s[84:85]", "s84", "s85", w, 62, 63);
    PKFMA_ONLY(ac2, Mp[30], "s[80:81]");
    PKFMA_ONLY(ac3, Mp[31], "s[84:85]");
    f32x2 t0, t1, tt;
    asm("v_pk_add_f32 %0, %1, %2" : "=v"(t0) : "v"(ac0), "v"(ac1));
    asm("v_pk_add_f32 %0, %1, %2" : "=v"(t1) : "v"(ac2), "v"(ac3));
    asm("v_pk_add_f32 %0, %1, %2" : "=v"(tt) : "v"(t0), "v"(t1));
    float s = tt.x + tt.y;
    score2 = emit2 + anch + __builtin_amdgcn_logf(s);  // v_log_f32 = log2
  };

  // Software-pipelined emissions (pre-scaled by log2e), 8 deep.
  float eb[8];
#pragma unroll
  for (int u = 0; u < 8; ++u) {
    int t0 = 1 + u;
    int tc = t0 < T ? t0 : T - 1;
    eb[u] = hb[(size_t)tc * N + lane] * LOG2E;
  }

  int t = 1;
  for (; t + 8 <= len; t += 8) {
#pragma unroll
    for (int u = 0; u < 8; ++u) {
      step(eb[u]);
      int tn = t + u + 8;
      int tc = tn < T ? tn : T - 1;  // in-bounds; value unused past len
      eb[u] = hb[(size_t)tc * N + lane] * LOG2E;
    }
  }
  for (; t < len; ++t) {  // <=7 tail steps
    step(hb[(size_t)t * N + lane] * LOG2E);
  }

  // Terminal transition to END (N-1), then wave-wide logsumexp (natural log out).
  float fin = score2 * LN2 + trans[(N - 1) * N + lane];
  float m = fin;
#pragma unroll
  for (int off = 32; off >= 1; off >>= 1)
    m = fmaxf(m, __shfl_xor(m, off, 64));
  float z = __builtin_amdgcn_exp2f((fin - m) * LOG2E);
#pragma unroll
  for (int off = 32; off >= 1; off >>= 1)
    z += __shfl_xor(z, off, 64);
  if (lane == 0) out[b] = m + LN2 * __builtin_amdgcn_logf(z);
}

extern "C" void kernel_launch(void* const* d_in, const int* in_sizes, int n_in,
                              void* d_out, int out_size, void* d_ws, size_t ws_size,
                              hipStream_t stream) {
  const float* h = (const float*)d_in[0];
  const float* trans = (const float*)d_in[1];
  const int* lengths = (const int*)d_in[2];
  float* out = (float*)d_out;
  const int B = in_sizes[2];
  const int N = 64;
  const int T = in_sizes[0] / (B * N);
  crf_fwd_33852932227637<<<B, 64, 0, stream>>>(h, trans, lengths, out, T);
}

// Round 4
// 433.995 us; speedup vs baseline: 1.0677x; 1.0677x over previous
//
#include <hip/hip_runtime.h>

#define LOG2E 1.4426950408889634f
#define LN2   0.6931471805599453f

// One wave (64 lanes) per batch element. Lane i owns state i.
// LINEAR-domain recurrence (round-5 restructure): p = exp2(score2) is a
// linear state:  p_{t+1} = D_t (.) (M p_t),  D_t = exp(emit_t), M = exp(trans).
// This removes exp2/log2/readfirstlane from the per-step serial path entirely
// (round-2 counters: 583 cyc/step vs ~290 issue cycles -> ~293 cyc of serial
// stall, dominated by the transcendental head/tail). Range is managed by an
// every-4-steps renormalization using only integer exponent ops:
//   e = exponent(readfirstlane(p)); p *= 2^(127-e); base2 += e-127.
// s[0] is within ~2^20 of the max lane (s[0] >= max_j w_j * min_j M[0,j]),
// so the anchor slop is harmless and the bookkeeping is exact for any e.
// Worst-case growth per step <= max(D)*max(rowsum) ~= 2^17; 4 steps + slop
// stays far below 2^127. Components <2^-126 of the max flush to zero, same
// information loss class as the reference's exp(x - max) underflow.
//
// Round-3 post-mortem: hand-asm v_pk_fma with SGPR-pair broadcast was both
// slower (VOP3P + 64b scalar operand issue penalty) and WRONG (SGPR RAW
// hazard invisible to the compiler inside asm blocks -> absmax 32). All asm
// scheduling removed; plain fmaf + readlane (round-2's verified codegen).
__device__ __forceinline__ float bcast(float v, int l) {
  return __uint_as_float(__builtin_amdgcn_readlane(__float_as_uint(v), l));
}

__global__ __launch_bounds__(64)
__attribute__((amdgpu_waves_per_eu(1, 1)))
void crf_fwd_33852932227637(
    const float* __restrict__ h,
    const float* __restrict__ trans,
    const int* __restrict__ lengths,
    float* __restrict__ out,
    int T) {
  constexpr int N = 64;
  const int b = blockIdx.x;
  const int lane = threadIdx.x;

  const float* hb = h + (size_t)b * T * N;

  // M row for this lane: M[lane][j] = exp(trans[lane*64+j])  (64 VGPRs)
  float Mrow[N];
  const float4* trow = (const float4*)(trans + lane * N);
#pragma unroll
  for (int q = 0; q < 16; ++q) {
    float4 tq = trow[q];
    Mrow[4 * q + 0] = __builtin_amdgcn_exp2f(tq.x * LOG2E);
    Mrow[4 * q + 1] = __builtin_amdgcn_exp2f(tq.y * LOG2E);
    Mrow[4 * q + 2] = __builtin_amdgcn_exp2f(tq.z * LOG2E);
    Mrow[4 * q + 3] = __builtin_amdgcn_exp2f(tq.w * LOG2E);
  }
  // Pin into arch VGPRs (round-2 confirmed: without this the backend parks
  // Mrow in AGPRs/scratch; VGPR_Count 48 -> 132 and -5% time).
#pragma unroll
  for (int q = 0; q < 8; ++q) {
    asm volatile("" : "+v"(Mrow[8 * q + 0]), "+v"(Mrow[8 * q + 1]),
                      "+v"(Mrow[8 * q + 2]), "+v"(Mrow[8 * q + 3]),
                      "+v"(Mrow[8 * q + 4]), "+v"(Mrow[8 * q + 5]),
                      "+v"(Mrow[8 * q + 6]), "+v"(Mrow[8 * q + 7]));
  }

  const int len = lengths[b];

  // t=0 closed form: score[i] = h[b,0,i] + trans[i,START]  ->  p = 2^score2
  float p = __builtin_amdgcn_exp2f((hb[lane] + trans[lane * N + (N - 2)]) * LOG2E);
  int base2 = 0;

  auto step = [&](float D) {
    float a0 = 0.f, a1 = 0.f, a2 = 0.f, a3 = 0.f;
#pragma unroll
    for (int j = 0; j < N; j += 4) {
      a0 = fmaf(Mrow[j + 0], bcast(p, j + 0), a0);
      a1 = fmaf(Mrow[j + 1], bcast(p, j + 1), a1);
      a2 = fmaf(Mrow[j + 2], bcast(p, j + 2), a2);
      a3 = fmaf(Mrow[j + 3], bcast(p, j + 3), a3);
    }
    p = ((a0 + a1) + (a2 + a3)) * D;
  };

  auto rescale = [&]() {
    unsigned bits = __builtin_amdgcn_readfirstlane(__float_as_uint(p));
    int e = (int)((bits >> 23) & 0xffu);
    base2 += e - 127;
    p *= __uint_as_float((unsigned)(254 - e) << 23);  // 2^(127-e), exact
  };

  // Software-pipelined D_t = exp(emit_t), 8 deep (exp2 is off the serial
  // path here: computed 8 steps ahead of use).
  float eb[8];
#pragma unroll
  for (int u = 0; u < 8; ++u) {
    int t0 = 1 + u;
    int tc = t0 < T ? t0 : T - 1;
    eb[u] = __builtin_amdgcn_exp2f(hb[(size_t)tc * N + lane] * LOG2E);
  }

  int t = 1;
  for (; t + 8 <= len; t += 8) {
#pragma unroll
    for (int u = 0; u < 8; ++u) {
      step(eb[u]);
      if (u == 3 || u == 7) rescale();
      int tn = t + u + 8;
      int tc = tn < T ? tn : T - 1;  // in-bounds; value unused past len
      eb[u] = __builtin_amdgcn_exp2f(hb[(size_t)tc * N + lane] * LOG2E);
    }
  }
  // Tail (<=7 steps). Loop above exits with t ≡ 1 (mod 8); slot for time t
  // is (t-1)&7. Rescale every step (rare path, cheap).
  for (; t < len; ++t) {
    step(eb[(t - 1) & 7]);
    rescale();
  }

  // score2 = log2(p) + base2; terminal transition to END; wave-wide lse.
  float score2 = __builtin_amdgcn_logf(p) + (float)base2;
  float fin = score2 * LN2 + trans[(N - 1) * N + lane];
  float m = fin;
#pragma unroll
  for (int off = 32; off >= 1; off >>= 1)
    m = fmaxf(m, __shfl_xor(m, off, 64));
  float z = __builtin_amdgcn_exp2f((fin - m) * LOG2E);
#pragma unroll
  for (int off = 32; off >= 1; off >>= 1)
    z += __shfl_xor(z, off, 64);
  if (lane == 0) out[b] = m + LN2 * __builtin_amdgcn_logf(z);
}

extern "C" void kernel_launch(void* const* d_in, const int* in_sizes, int n_in,
                              void* d_out, int out_size, void* d_ws, size_t ws_size,
                              hipStream_t stream) {
  const float* h = (const float*)d_in[0];
  const float* trans = (const float*)d_in[1];
  const int* lengths = (const int*)d_in[2];
  float* out = (float*)d_out;
  const int B = in_sizes[2];
  const int N = 64;
  const int T = in_sizes[0] / (B * N);
  crf_fwd_33852932227637<<<B, 64, 0, stream>>>(h, trans, lengths, out, T);
}

// Round 5
// 281.620 us; speedup vs baseline: 1.6455x; 1.5411x over previous
//
#include <hip/hip_runtime.h>

#define LOG2E 1.4426950408889634f
#define LN2   0.6931471805599453f

// Forward/backward split (round-5 restructure): the dispatch is pinned by the
// longest chain (len==T==1024) at ~675 cyc/step. Z factorizes at any t:
//   Z = beta_m^T alpha_m,
//   alpha_t = D_t M alpha_{t-1}         (forward,  alpha_0 = D_0 v_START)
//   beta_{t-1} = M^T (d_t . beta_t)     (backward, beta_{len-1} = u_END)
// Wave 0 runs the forward half (t=1..m), wave 1 the backward half
// (t=len-1..m+1) with M^T columns in registers; one LDS exchange + dot joins
// them. Serial critical path: 1024 -> 512 steps. Also doubles resident waves
// (1024 waves = 1 per SIMD chip-wide).
//
// Per-step structure is round-4's verified linear-domain matvec (absmax 0.0):
// p' = D (.) (M p), exponent-managed by an integer rescale every 4 steps.
// Round-2/3/4 established: the ~400 cyc/step stall is the readlane->SGPR->fma
// broadcast structure itself; this round cuts step COUNT, not step cost.
__device__ __forceinline__ float bcast(float v, int l) {
  return __uint_as_float(__builtin_amdgcn_readlane(__float_as_uint(v), l));
}

template <bool FWD>
__device__ __forceinline__ void run_chain(
    const float* __restrict__ hb, const float* __restrict__ trans,
    int lane, int len, int nsteps, int T, float& pOut, int& b2Out) {
  constexpr int N = 64;

  // M fragment: FWD lane i holds row i of M=exp(trans); BWD lane j holds
  // column j (i.e., row j of M^T). Prologue-only loads, L2-resident.
  float Mreg[N];
  if (FWD) {
    const float4* trow = (const float4*)(trans + lane * N);
#pragma unroll
    for (int q = 0; q < 16; ++q) {
      float4 tq = trow[q];
      Mreg[4 * q + 0] = __builtin_amdgcn_exp2f(tq.x * LOG2E);
      Mreg[4 * q + 1] = __builtin_amdgcn_exp2f(tq.y * LOG2E);
      Mreg[4 * q + 2] = __builtin_amdgcn_exp2f(tq.z * LOG2E);
      Mreg[4 * q + 3] = __builtin_amdgcn_exp2f(tq.w * LOG2E);
    }
  } else {
#pragma unroll
    for (int i = 0; i < N; ++i)
      Mreg[i] = __builtin_amdgcn_exp2f(trans[i * N + lane] * LOG2E);
  }
  // Pin into arch VGPRs (round-2: backend otherwise parks the array in
  // AGPRs/scratch; VGPR_Count 48->132 and measurable win).
#pragma unroll
  for (int q = 0; q < 8; ++q) {
    asm volatile("" : "+v"(Mreg[8 * q + 0]), "+v"(Mreg[8 * q + 1]),
                      "+v"(Mreg[8 * q + 2]), "+v"(Mreg[8 * q + 3]),
                      "+v"(Mreg[8 * q + 4]), "+v"(Mreg[8 * q + 5]),
                      "+v"(Mreg[8 * q + 6]), "+v"(Mreg[8 * q + 7]));
  }

  // Init: alpha_0[i] = exp(h[0,i] + trans[i,START]); beta_{len-1}[i] =
  // exp(trans[END,i]). START = N-2, END = N-1.
  float p;
  if (FWD)
    p = __builtin_amdgcn_exp2f((hb[lane] + trans[lane * N + (N - 2)]) * LOG2E);
  else
    p = __builtin_amdgcn_exp2f(trans[(N - 1) * N + lane] * LOG2E);
  int base2 = 0;

  auto step = [&](float D) {
    float src = FWD ? p : p * D;  // bwd: absorb d_t before M^T matvec
    float a0 = 0.f, a1 = 0.f, a2 = 0.f, a3 = 0.f;
#pragma unroll
    for (int j = 0; j < N; j += 4) {
      a0 = fmaf(Mreg[j + 0], bcast(src, j + 0), a0);
      a1 = fmaf(Mreg[j + 1], bcast(src, j + 1), a1);
      a2 = fmaf(Mreg[j + 2], bcast(src, j + 2), a2);
      a3 = fmaf(Mreg[j + 3], bcast(src, j + 3), a3);
    }
    float s = (a0 + a1) + (a2 + a3);
    p = FWD ? s * D : s;
  };

  auto rescale = [&]() {
    unsigned bits = __builtin_amdgcn_readfirstlane(__float_as_uint(p));
    int e = (int)((bits >> 23) & 0xffu);
    base2 += e - 127;
    p *= __uint_as_float((unsigned)(254 - e) << 23);  // 2^(127-e), exact
  };

  // Emission for logical step s: t = s (fwd) or t = len - s (bwd).
  // Clamp s into [1, max(nsteps,1)] for prefetch addresses (value unused
  // past nsteps; address stays in [0, T-1]).
  auto emit_of = [&](int s) -> float {
    int sc = s < nsteps ? s : nsteps;
    if (sc < 1) sc = 1;
    int t = FWD ? sc : len - sc;
    return __builtin_amdgcn_exp2f(hb[(size_t)t * N + lane] * LOG2E);
  };

  float eb[8];
#pragma unroll
  for (int u = 0; u < 8; ++u) eb[u] = emit_of(1 + u);

  int s = 1;
  for (; s + 8 <= nsteps + 1; s += 8) {  // full groups: steps s..s+7
#pragma unroll
    for (int u = 0; u < 8; ++u) {
      step(eb[u]);
      if (u == 3 || u == 7) rescale();
      eb[u] = emit_of(s + u + 8);
    }
  }
  // Tail (<=7). Loop exits with s ≡ 1 (mod 8); slot for step s is (s-1)&7.
  for (; s <= nsteps; ++s) {
    step(eb[(s - 1) & 7]);
    rescale();
  }

  pOut = p;
  b2Out = base2;
}

__global__ __launch_bounds__(128)
__attribute__((amdgpu_waves_per_eu(1, 1)))
void crf_fwd_33852932227637(
    const float* __restrict__ h,
    const float* __restrict__ trans,
    const int* __restrict__ lengths,
    float* __restrict__ out,
    int T) {
  constexpr int N = 64;
  const int b = blockIdx.x;
  const int lane = threadIdx.x & 63;
  const int wv = threadIdx.x >> 6;

  const float* hb = h + (size_t)b * T * N;
  const int len = lengths[b];
  const int m = (len - 1) >> 1;  // fwd steps: 1..m ; bwd steps: len-1..m+1

  float p;
  int b2;
  if (wv == 0)
    run_chain<true>(hb, trans, lane, len, m, T, p, b2);
  else
    run_chain<false>(hb, trans, lane, len, len - 1 - m, T, p, b2);

  __shared__ float xbeta[N];
  __shared__ int xb2;
  if (wv == 1) {
    xbeta[lane] = p;
    if (lane == 0) xb2 = b2;
  }
  __syncthreads();
  if (wv == 0) {
    // Z * 2^-(b2A+b2B) = sum_i alpha_m[i] * beta_m[i]; all terms >= 0,
    // anchors keep both factors ~2^0, so no over/underflow in the dot.
    float z = p * xbeta[lane];
#pragma unroll
    for (int off = 32; off >= 1; off >>= 1)
      z += __shfl_xor(z, off, 64);
    if (lane == 0)
      out[b] = LN2 * ((float)(b2 + xb2) + __builtin_amdgcn_logf(z));
  }
}

extern "C" void kernel_launch(void* const* d_in, const int* in_sizes, int n_in,
                              void* d_out, int out_size, void* d_ws, size_t ws_size,
                              hipStream_t stream) {
  const float* h = (const float*)d_in[0];
  const float* trans = (const float*)d_in[1];
  const int* lengths = (const int*)d_in[2];
  float* out = (float*)d_out;
  const int B = in_sizes[2];
  const int N = 64;
  const int T = in_sizes[0] / (B * N);
  crf_fwd_33852932227637<<<B, N * 2, 0, stream>>>(h, trans, lengths, out, T);
}

// Round 6
// 280.230 us; speedup vs baseline: 1.6536x; 1.0050x over previous
//
#include <hip/hip_runtime.h>

#define LOG2E 1.4426950408889634f
#define LN2   0.6931471805599453f

// Forward/backward split (round-5, verified: 151 µs, absmax 0): wave 0 runs
// alpha_t = D_t M alpha_{t-1} forward to the midpoint, wave 1 runs
// beta_{t-1} = M^T (d_t . beta_t) backward to the midpoint; one LDS exchange
// + dot joins them (Z = beta_m^T alpha_m). Linear domain, integer exponent
// rescale every 4 steps.
//
// Round-6 change: the step was 707 cyc vs ~290 issue cycles. All prior
// evidence (r2 residency fix, r4 transcendental removal: no effect) points
// at the remaining stall being the 64 adjacent v_readlane -> v_fma(SGPR)
// pairs: a VALU-writes-SGPR -> VALU-reads-SGPR dependency at distance ~2,
// ~6 cyc stall each. Fix: batch broadcasts in GROUPS OF 16 — 16 readlanes
// into 16 wave-uniform scalars (SGPRs), then 16 FMAs consuming them.
// Producer->consumer distance >=16 instrs swallows the hazard; 16 live
// SGPRs/group stays inside the scalar RF.
__device__ __forceinline__ float bcast(float v, int l) {
  return __uint_as_float(__builtin_amdgcn_readlane(__float_as_uint(v), l));
}

template <bool FWD>
__device__ __forceinline__ void run_chain(
    const float* __restrict__ hb, const float* __restrict__ trans,
    int lane, int len, int nsteps, int T, float& pOut, int& b2Out) {
  constexpr int N = 64;

  // M fragment: FWD lane i holds row i of M=exp(trans); BWD lane j holds
  // column j (row j of M^T). Prologue-only loads, L2-resident.
  float Mreg[N];
  if (FWD) {
    const float4* trow = (const float4*)(trans + lane * N);
#pragma unroll
    for (int q = 0; q < 16; ++q) {
      float4 tq = trow[q];
      Mreg[4 * q + 0] = __builtin_amdgcn_exp2f(tq.x * LOG2E);
      Mreg[4 * q + 1] = __builtin_amdgcn_exp2f(tq.y * LOG2E);
      Mreg[4 * q + 2] = __builtin_amdgcn_exp2f(tq.z * LOG2E);
      Mreg[4 * q + 3] = __builtin_amdgcn_exp2f(tq.w * LOG2E);
    }
  } else {
#pragma unroll
    for (int i = 0; i < N; ++i)
      Mreg[i] = __builtin_amdgcn_exp2f(trans[i * N + lane] * LOG2E);
  }
  // Pin into arch VGPRs (round-2: backend otherwise parks the array in
  // AGPRs/scratch).
#pragma unroll
  for (int q = 0; q < 8; ++q) {
    asm volatile("" : "+v"(Mreg[8 * q + 0]), "+v"(Mreg[8 * q + 1]),
                      "+v"(Mreg[8 * q + 2]), "+v"(Mreg[8 * q + 3]),
                      "+v"(Mreg[8 * q + 4]), "+v"(Mreg[8 * q + 5]),
                      "+v"(Mreg[8 * q + 6]), "+v"(Mreg[8 * q + 7]));
  }

  // Init: alpha_0[i] = exp(h[0,i] + trans[i,START]); beta_{len-1}[i] =
  // exp(trans[END,i]). START = N-2, END = N-1.
  float p;
  if (FWD)
    p = __builtin_amdgcn_exp2f((hb[lane] + trans[lane * N + (N - 2)]) * LOG2E);
  else
    p = __builtin_amdgcn_exp2f(trans[(N - 1) * N + lane] * LOG2E);
  int base2 = 0;

  auto step = [&](float D) {
    float src = FWD ? p : p * D;  // bwd: absorb d_t before M^T matvec
    float a0 = 0.f, a1 = 0.f, a2 = 0.f, a3 = 0.f;
#pragma unroll
    for (int g = 0; g < 4; ++g) {
      // Batch of 16 broadcasts: readlane results are wave-uniform -> SGPRs.
      float w[16];
#pragma unroll
      for (int k = 0; k < 16; ++k) w[k] = bcast(src, 16 * g + k);
      // Then 16 FMAs, each reading one SGPR (>=16-instr hazard distance).
#pragma unroll
      for (int k = 0; k < 16; k += 4) {
        a0 = fmaf(Mreg[16 * g + k + 0], w[k + 0], a0);
        a1 = fmaf(Mreg[16 * g + k + 1], w[k + 1], a1);
        a2 = fmaf(Mreg[16 * g + k + 2], w[k + 2], a2);
        a3 = fmaf(Mreg[16 * g + k + 3], w[k + 3], a3);
      }
    }
    float s = (a0 + a1) + (a2 + a3);
    p = FWD ? s * D : s;
  };

  auto rescale = [&]() {
    unsigned bits = __builtin_amdgcn_readfirstlane(__float_as_uint(p));
    int e = (int)((bits >> 23) & 0xffu);
    base2 += e - 127;
    p *= __uint_as_float((unsigned)(254 - e) << 23);  // 2^(127-e), exact
  };

  // Emission for logical step s: t = s (fwd) or t = len - s (bwd).
  // Clamp s into [1, nsteps] for prefetch addresses (value unused past
  // nsteps; address stays in [0, T-1]).
  auto emit_of = [&](int s) -> float {
    int sc = s < nsteps ? s : nsteps;
    if (sc < 1) sc = 1;
    int t = FWD ? sc : len - sc;
    return __builtin_amdgcn_exp2f(hb[(size_t)t * N + lane] * LOG2E);
  };

  float eb[8];
#pragma unroll
  for (int u = 0; u < 8; ++u) eb[u] = emit_of(1 + u);

  int s = 1;
  for (; s + 8 <= nsteps + 1; s += 8) {  // full groups: steps s..s+7
#pragma unroll
    for (int u = 0; u < 8; ++u) {
      step(eb[u]);
      if (u == 3 || u == 7) rescale();
      eb[u] = emit_of(s + u + 8);
    }
  }
  // Tail (<=7). Loop exits with s ≡ 1 (mod 8); slot for step s is (s-1)&7.
  for (; s <= nsteps; ++s) {
    step(eb[(s - 1) & 7]);
    rescale();
  }

  pOut = p;
  b2Out = base2;
}

__global__ __launch_bounds__(128)
__attribute__((amdgpu_waves_per_eu(1, 1)))
void crf_fwd_33852932227637(
    const float* __restrict__ h,
    const float* __restrict__ trans,
    const int* __restrict__ lengths,
    float* __restrict__ out,
    int T) {
  constexpr int N = 64;
  const int b = blockIdx.x;
  const int lane = threadIdx.x & 63;
  const int wv = threadIdx.x >> 6;

  const float* hb = h + (size_t)b * T * N;
  const int len = lengths[b];
  const int m = (len - 1) >> 1;  // fwd steps: 1..m ; bwd steps: len-1..m+1

  float p;
  int b2;
  if (wv == 0)
    run_chain<true>(hb, trans, lane, len, m, T, p, b2);
  else
    run_chain<false>(hb, trans, lane, len, len - 1 - m, T, p, b2);

  __shared__ float xbeta[N];
  __shared__ int xb2;
  if (wv == 1) {
    xbeta[lane] = p;
    if (lane == 0) xb2 = b2;
  }
  __syncthreads();
  if (wv == 0) {
    // Z * 2^-(b2A+b2B) = sum_i alpha_m[i] * beta_m[i]; all terms >= 0,
    // anchors keep both factors ~2^0, so no over/underflow in the dot.
    float z = p * xbeta[lane];
#pragma unroll
    for (int off = 32; off >= 1; off >>= 1)
      z += __shfl_xor(z, off, 64);
    if (lane == 0)
      out[b] = LN2 * ((float)(b2 + xb2) + __builtin_amdgcn_logf(z));
  }
}

extern "C" void kernel_launch(void* const* d_in, const int* in_sizes, int n_in,
                              void* d_out, int out_size, void* d_ws, size_t ws_size,
                              hipStream_t stream) {
  const float* h = (const float*)d_in[0];
  const float* trans = (const float*)d_in[1];
  const int* lengths = (const int*)d_in[2];
  float* out = (float*)d_out;
  const int B = in_sizes[2];
  const int N = 64;
  const int T = in_sizes[0] / (B * N);
  crf_fwd_33852932227637<<<B, N * 2, 0, stream>>>(h, trans, lengths, out, T);
}

// Round 7
// 269.525 us; speedup vs baseline: 1.7193x; 1.0397x over previous
//
#include <hip/hip_runtime.h>

#define LOG2E 1.4426950408889634f
#define LN2   0.6931471805599453f

// Fwd/bwd split (r5, verified): wave 0 runs alpha_t = D_t M alpha_{t-1} to the
// midpoint, wave 1 runs beta_{t-1} = M^T (d_t . beta_t) down to it; join with
// one dot (Z = beta_m^T alpha_m). Linear domain, integer-exponent rescale.
//
// Round-7 change: r6's readlane-batching was NEUTRAL -> the stall is the
// v_readlane op itself (~8 cyc/op: 64x8 + 64 fma x2 + misc = ~700 = measured
// 707 cyc/step). Broadcast mechanism replaced: state lives in a per-wave LDS
// buffer; each step does 16x ds_read_b128 at WAVE-UNIFORM addresses
// (same-address = broadcast, conflict-free, DS pipe) delivering all 64 p
// values to every lane; 64 full-rate VGPR*VGPR FMAs against the private M
// row; one per-lane ds_write_b32 of the new state. Single wave owns its
// buffer -> no barriers; same-wave DS ops are in-order. The bwd chain folds
// its emission at WRITE time (w = d_t . beta_t), so the broadcast operand
// never needs a non-lane-aligned D. Rescale anchor = broadcast p[0]
// (identical in all lanes): no readfirstlane; scale folds into the D mul,
// off the critical path; every 2 steps for range margin.
template <bool FWD>
__device__ __forceinline__ void run_chain(
    const float* __restrict__ hb, const float* __restrict__ trans,
    float* __restrict__ pbuf, int lane, int len, int nsteps, int& b2Out) {
  constexpr int N = 64;

  // M fragment: FWD lane i holds row i of M=exp(trans); BWD lane j holds
  // column j (row j of M^T). Prologue-only loads, L2/L3-resident.
  float Mreg[N];
  if (FWD) {
    const float4* trow = (const float4*)(trans + lane * N);
#pragma unroll
    for (int q = 0; q < 16; ++q) {
      float4 tq = trow[q];
      Mreg[4 * q + 0] = __builtin_amdgcn_exp2f(tq.x * LOG2E);
      Mreg[4 * q + 1] = __builtin_amdgcn_exp2f(tq.y * LOG2E);
      Mreg[4 * q + 2] = __builtin_amdgcn_exp2f(tq.z * LOG2E);
      Mreg[4 * q + 3] = __builtin_amdgcn_exp2f(tq.w * LOG2E);
    }
  } else {
#pragma unroll
    for (int i = 0; i < N; ++i)
      Mreg[i] = __builtin_amdgcn_exp2f(trans[i * N + lane] * LOG2E);
  }
  // Pin into arch VGPRs (r2: backend otherwise parks the array in AGPRs).
#pragma unroll
  for (int q = 0; q < 8; ++q) {
    asm volatile("" : "+v"(Mreg[8 * q + 0]), "+v"(Mreg[8 * q + 1]),
                      "+v"(Mreg[8 * q + 2]), "+v"(Mreg[8 * q + 3]),
                      "+v"(Mreg[8 * q + 4]), "+v"(Mreg[8 * q + 5]),
                      "+v"(Mreg[8 * q + 6]), "+v"(Mreg[8 * q + 7]));
  }

  // Init state in LDS. FWD: alpha_0[i] = exp(h[0,i]+trans[i,START]).
  // BWD: u_END[i] = exp(trans[END,i]); if there is at least one matvec,
  // fold d_{len-1} now (write-folded scheme). START=N-2, END=N-1.
  {
    float v;
    if (FWD) {
      v = __builtin_amdgcn_exp2f((hb[lane] + trans[lane * N + (N - 2)]) * LOG2E);
    } else {
      v = __builtin_amdgcn_exp2f(trans[(N - 1) * N + lane] * LOG2E);
      if (nsteps >= 1)
        v *= __builtin_amdgcn_exp2f(hb[(size_t)(len - 1) * N + lane] * LOG2E);
    }
    pbuf[lane] = v;
  }
  int base2 = 0;

  // Folded-step count: FWD runs all nsteps with D applied after the matvec;
  // BWD runs nsteps-1 with D folded at write, then one final RAW step
  // (beta_m must exclude d_m).
  const int ns = FWD ? nsteps : nsteps - 1;

  auto step = [&](float D, bool resc) {
    const float4* pb4 = (const float4*)pbuf;
    float a[8] = {0.f, 0.f, 0.f, 0.f, 0.f, 0.f, 0.f, 0.f};
    float p0ref = 0.f;
#pragma unroll
    for (int g = 0; g < 16; ++g) {
      float4 q = pb4[g];  // uniform address -> ds_read_b128 broadcast
      if (g == 0) p0ref = q.x;
      const int b0 = (4 * g) & 7;
      a[b0 + 0] = fmaf(Mreg[4 * g + 0], q.x, a[b0 + 0]);
      a[b0 + 1] = fmaf(Mreg[4 * g + 1], q.y, a[b0 + 1]);
      a[b0 + 2] = fmaf(Mreg[4 * g + 2], q.z, a[b0 + 2]);
      a[b0 + 3] = fmaf(Mreg[4 * g + 3], q.w, a[b0 + 3]);
    }
    float mult = D;
    if (resc) {  // anchor = replicated p[0]; slop vs max lane bounded ~2^33
      unsigned bits = __float_as_uint(p0ref);
      int e = (int)((bits >> 23) & 0xffu);
      base2 += e - 127;
      mult *= __uint_as_float((unsigned)(254 - e) << 23);  // 2^(127-e)
    }
    float s = ((a[0] + a[1]) + (a[2] + a[3])) + ((a[4] + a[5]) + (a[6] + a[7]));
    pbuf[lane] = s * mult;  // per-lane write, 2-way bank alias = free
  };

  // Emission for folded step s: FWD t = s; BWD t = len-1-s (write-fold).
  auto emit_of = [&](int s_) -> float {
    int smax = ns < 1 ? 1 : ns;
    int sc = s_ < smax ? s_ : smax;
    if (sc < 1) sc = 1;
    int t = FWD ? sc : (len - 1 - sc);
    if (t < 0) t = 0;  // value unused in these cases; keep address in range
    return __builtin_amdgcn_exp2f(hb[(size_t)t * N + lane] * LOG2E);
  };

  float eb[8];
#pragma unroll
  for (int u = 0; u < 8; ++u) eb[u] = emit_of(1 + u);

  int s = 1;
  for (; s + 8 <= ns + 1; s += 8) {
#pragma unroll
    for (int u = 0; u < 8; ++u) {
      step(eb[u], (u & 1) == 1);  // rescale every 2 steps
      eb[u] = emit_of(s + u + 8);
    }
  }
  for (; s <= ns; ++s) {  // tail; slot for step s is (s-1)&7 (loop exits s==1 mod 8)
    step(eb[(s - 1) & 7], true);
  }
  if (!FWD && nsteps >= 1) step(1.0f, true);  // final raw beta_m step

  b2Out = base2;
}

__global__ __launch_bounds__(128)
__attribute__((amdgpu_waves_per_eu(1, 1)))
void crf_fwd_33852932227637(
    const float* __restrict__ h,
    const float* __restrict__ trans,
    const int* __restrict__ lengths,
    float* __restrict__ out,
    int T) {
  constexpr int N = 64;
  const int b = blockIdx.x;
  const int lane = threadIdx.x & 63;
  const int wv = threadIdx.x >> 6;

  const float* hb = h + (size_t)b * T * N;
  const int len = lengths[b];
  const int m = (len - 1) >> 1;  // fwd matvecs: 1..m ; bwd matvecs: len-1..m+1

  __shared__ __align__(16) float pbuf[2][N];
  __shared__ int xb2[2];

  int b2;
  if (wv == 0)
    run_chain<true>(hb, trans, pbuf[0], lane, len, m, b2);
  else
    run_chain<false>(hb, trans, pbuf[1], lane, len, len - 1 - m, b2);
  if (lane == 0) xb2[wv] = b2;
  __syncthreads();

  if (wv == 0) {
    // Z * 2^-(b2f+b2b) = sum_i alpha_m[i] * beta_m[i]; anchors keep both
    // factors ~2^0 (spread <=~2^33), so the dot neither over- nor underflows.
    float z = pbuf[0][lane] * pbuf[1][lane];
#pragma unroll
    for (int off = 32; off >= 1; off >>= 1)
      z += __shfl_xor(z, off, 64);
    if (lane == 0)
      out[b] = LN2 * ((float)(xb2[0] + xb2[1]) + __builtin_amdgcn_logf(z));
  }
}

extern "C" void kernel_launch(void* const* d_in, const int* in_sizes, int n_in,
                              void* d_out, int out_size, void* d_ws, size_t ws_size,
                              hipStream_t stream) {
  const float* h = (const float*)d_in[0];
  const float* trans = (const float*)d_in[1];
  const int* lengths = (const int*)d_in[2];
  float* out = (float*)d_out;
  const int B = in_sizes[2];
  const int N = 64;
  const int T = in_sizes[0] / (B * N);
  crf_fwd_33852932227637<<<B, N * 2, 0, stream>>>(h, trans, lengths, out, T);
}